// Round 3
// baseline (526.781 us; speedup 1.0000x reference)
//
#include <hip/hip_runtime.h>
#include <hip/hip_bf16.h>
#include <math.h>

#define Bn 4
#define Nn 2048
#define FIN 128
#define Hh 4
#define HIDn 32
#define En 4
#define ZS 64            // i-splits in pass 1
#define RPT (Nn / ZS)    // 32 rows per thread

typedef __bf16 bf16x8 __attribute__((ext_vector_type(8)));
typedef float  f32x4  __attribute__((ext_vector_type(4)));

// K1: ht = h @ W  (B,N,128); emit htT bf16 [b][h][hid][n], s_i/s_j fp32 [b][h][n]
__global__ __launch_bounds__(256) void k1_proj(const float* __restrict__ h,
    const float* __restrict__ W, const float* __restrict__ a,
    __bf16* __restrict__ htT, float* __restrict__ s_i, float* __restrict__ s_j)
{
    __shared__ float hl[16][FIN];
    const int b  = blockIdx.y;
    const int n0 = blockIdx.x * 16;
    const int t  = threadIdx.x;
    for (int k = t; k < 16 * FIN; k += 256) {
        int r = k >> 7, f = k & 127;
        hl[r][f] = h[((size_t)(b * Nn + n0 + r)) * FIN + f];
    }
    __syncthreads();
    const int d   = t & 127;
    const int ng  = t >> 7;
    const int hh  = d >> 5;
    const int hid = d & 31;
    float acc[8];
#pragma unroll
    for (int r = 0; r < 8; r++) acc[r] = 0.f;
    for (int f = 0; f < FIN; f++) {
        float wv = W[f * 128 + d];
#pragma unroll
        for (int r = 0; r < 8; r++) acc[r] = fmaf(hl[ng * 8 + r][f], wv, acc[r]);
    }
    const float ai = a[hh * 68 + hid];
    const float aj = a[hh * 68 + 32 + hid];
#pragma unroll
    for (int r = 0; r < 8; r++) {
        float vi = acc[r] * ai;
        float vj = acc[r] * aj;
#pragma unroll
        for (int m = 16; m >= 1; m >>= 1) {
            vi += __shfl_xor(vi, m, 64);
            vj += __shfl_xor(vj, m, 64);
        }
        if (hid == 0) {
            int n = n0 + ng * 8 + r;
            s_i[(b * Hh + hh) * Nn + n] = vi;
            s_j[(b * Hh + hh) * Nn + n] = vj;
        }
    }
    bf16x8 pack;
#pragma unroll
    for (int r = 0; r < 8; r++) pack[r] = (__bf16)acc[r];
    *(bf16x8*)(htT + ((size_t)((b * Hh + hh) * HIDn + hid)) * Nn + n0 + ng * 8) = pack;
}

// K2: P[b][h][i][j] = adj ? exp(s_i + s_j + edge.a_e) : 0  (bf16, unnormalized)
//     Dpart[b][h][z][j] = partial column sums over this block's i-range
__global__ __launch_bounds__(256) void k2_pexp(const float* __restrict__ edge,
    const int* __restrict__ adj, const float* __restrict__ a,
    const float* __restrict__ s_i, const float* __restrict__ s_j,
    __bf16* __restrict__ P, float* __restrict__ Dpart)
{
    __shared__ float si_l[4][RPT];
    const int b  = blockIdx.y;
    const int z  = blockIdx.z;
    const int i0 = z * RPT;
    const int t  = threadIdx.x;
    const int j  = blockIdx.x * 256 + t;
    if (t < 4 * RPT) si_l[t >> 5][t & (RPT - 1)] = s_i[(b * Hh + (t >> 5)) * Nn + i0 + (t & (RPT - 1))];
    float ae[4][4];
#pragma unroll
    for (int hh = 0; hh < 4; hh++)
#pragma unroll
        for (int e = 0; e < 4; e++) ae[hh][e] = a[hh * 68 + 64 + e];
    float sj[4];
#pragma unroll
    for (int hh = 0; hh < 4; hh++) sj[hh] = s_j[(b * Hh + hh) * Nn + j];
    __syncthreads();
    float D[4] = {0.f, 0.f, 0.f, 0.f};
#pragma unroll 4
    for (int ii = 0; ii < RPT; ii++) {
        const int i = i0 + ii;
        const size_t pr = ((size_t)(b * Nn + i)) * Nn + j;
        const f32x4 e4 = __builtin_nontemporal_load((const f32x4*)(edge + pr * En));
        const int av = __builtin_nontemporal_load(adj + pr);
#pragma unroll
        for (int hh = 0; hh < 4; hh++) {
            float dot = e4.x * ae[hh][0] + e4.y * ae[hh][1] + e4.z * ae[hh][2] + e4.w * ae[hh][3];
            float p = (av > 0) ? __expf(si_l[hh][ii] + sj[hh] + dot) : 0.f;
            D[hh] += p;
            __builtin_nontemporal_store((__bf16)p, P + ((size_t)((b * Hh + hh) * Nn + i)) * Nn + j);
        }
    }
#pragma unroll
    for (int hh = 0; hh < 4; hh++)
        Dpart[((size_t)((b * Hh + hh) * ZS + z)) * Nn + j] = D[hh];
}

// K3a: rD[bh][j] = 1 / sum_z Dpart
__global__ __launch_bounds__(256) void k3a_rd(const float* __restrict__ Dpart,
    float* __restrict__ rD)
{
    const int idx = blockIdx.x * 256 + threadIdx.x;  // bh*Nn + j
    const int j   = idx & (Nn - 1);
    const int bh  = idx >> 11;
    float S = 0.f;
#pragma unroll
    for (int z = 0; z < ZS; z++) S += Dpart[((size_t)(bh * ZS + z)) * Nn + j];
    rD[idx] = (S > 0.f) ? 1.f / S : 0.f;
}

// K3b: htD[bh][d][j] = htT[bh][d][j] * rD[bh][j]
__global__ __launch_bounds__(256) void k3b_scale(const float* __restrict__ rD,
    const __bf16* __restrict__ htT, __bf16* __restrict__ htD)
{
    const int idx = blockIdx.x * 256 + threadIdx.x;  // ((bh*HID + d)*Nn + j)
    const int j   = idx & (Nn - 1);
    const int bh  = idx >> 16;                       // 11 (j) + 5 (d)
    const float r = rD[bh * Nn + j];
    htD[idx] = (__bf16)((float)htT[idx] * r);
}

// K4: out[b][i][h*32+d] = sum_j P[bh][i][j] * htD[bh][d][j]
// wave = 16x16 output tile; block = 2 i-subtiles x 2 col-halves
__global__ __launch_bounds__(256) void k4_gemm(const __bf16* __restrict__ P,
    const __bf16* __restrict__ htD, float* __restrict__ out)
{
    const int bh   = blockIdx.y;
    const int t    = threadIdx.x;
    const int w    = t >> 6;
    const int wi   = w >> 1;
    const int wc   = w & 1;
    const int lane = t & 63;
    const int quad = lane >> 4;
    const int lrow = lane & 15;
    const int i0   = blockIdx.x * 32 + wi * 16;

    const __bf16* Arow = P   + (size_t)bh * Nn * Nn + (size_t)(i0 + lrow) * Nn + quad * 8;
    const __bf16* Bp   = htD + (size_t)bh * HIDn * Nn + (size_t)(wc * 16 + lrow) * Nn + quad * 8;

    f32x4 acc = {0.f, 0.f, 0.f, 0.f};
#pragma unroll 8
    for (int k0 = 0; k0 < Nn; k0 += 32) {
        bf16x8 af = *(const bf16x8*)(Arow + k0);
        bf16x8 bf = *(const bf16x8*)(Bp + k0);
        acc = __builtin_amdgcn_mfma_f32_16x16x32_bf16(af, bf, acc, 0, 0, 0);
    }
    const int b = bh >> 2, hh = bh & 3;
#pragma unroll
    for (int r = 0; r < 4; r++) {
        const int i = i0 + quad * 4 + r;
        out[((size_t)(b * Nn + i)) * 128 + hh * 32 + wc * 16 + lrow] = acc[r];
    }
}

extern "C" void kernel_launch(void* const* d_in, const int* in_sizes, int n_in,
                              void* d_out, int out_size, void* d_ws, size_t ws_size,
                              hipStream_t stream)
{
    const float* h    = (const float*)d_in[0];
    const int*   adj  = (const int*)d_in[1];
    const float* edge = (const float*)d_in[2];
    const float* W    = (const float*)d_in[3];
    const float* a    = (const float*)d_in[4];
    float* out = (float*)d_out;

    char* ws = (char*)d_ws;
    __bf16* htT   = (__bf16*)(ws);                   //  2,097,152 B
    __bf16* htD   = (__bf16*)(ws + 2097152);         //  2,097,152 B
    float*  s_i   = (float*)(ws + 4194304);          //    131,072 B
    float*  s_j   = (float*)(ws + 4325376);          //    131,072 B
    float*  rD    = (float*)(ws + 4456448);          //    131,072 B
    float*  Dpart = (float*)(ws + 4587520);          //  8,388,608 B
    __bf16* P     = (__bf16*)(ws + 16777216);        // 134,217,728 B  (total ~151 MB)

    k1_proj  <<<dim3(Nn / 16, Bn),       256, 0, stream>>>(h, W, a, htT, s_i, s_j);
    k2_pexp  <<<dim3(Nn / 256, Bn, ZS),  256, 0, stream>>>(edge, adj, a, s_i, s_j, P, Dpart);
    k3a_rd   <<<dim3(Bn * Hh * Nn / 256), 256, 0, stream>>>(Dpart, rD);
    k3b_scale<<<dim3(Bn * Hh * HIDn * Nn / 256), 256, 0, stream>>>(rD, htT, htD);
    k4_gemm  <<<dim3(Nn / 32, Bn * Hh),  256, 0, stream>>>(P, htD, out);
}